// Round 7
// baseline (389.036 us; speedup 1.0000x reference)
//
#include <hip/hip_runtime.h>
#include <stdint.h>

// Spiking ConvColumn: temporal PWL-response conv + winner-takes-all.
//   input_spikes [16, 2, 64, 64, 100] fp32 (binary)
//   weight       [32, 2, 3, 3]        fp32 in [0,1]
//   output       [16, 32, 31, 31, 149] fp32 (one-hot spikes)
#define NXS 31
#define NYS 31
#define TP 149
#define TT 100
#define RSTRIDE 108         // u32/row; word W = entry W-4 (4 zero front-pad
                            // words = entries -4..-1; entries 101..103 = dup
                            // T[100]); %4==0 keeps b128 alignment
#define NROWS 54            // 2 ci * 3 ky * 9 cols (4 sites share 9 cols)
#define NSUM 8              // per-(site,half) precomputed sum rows
                            // LDS = 62*108*4 = 26.8 KB -> 6 blk/CU
#define NBLK (16 * NYS * 8) // 3968 blocks
#define NREC (NBLK * 128)   // 492032 (site,ch) mask records in d_ws
#define RLEN (NXS * TP)     // 4619 floats per (b,ch,y) output strip

// argmax over 32 channels; ties -> lowest ch (jnp.argmax); both halves hold
// the combined pot, shuffles with mk<=16 stay inside each half.
#define RECORD_WIN(POTV, TIDX)                                           \
    {                                                                    \
        float v_ = (POTV); int c_ = ch;                                  \
        _Pragma("unroll")                                                \
        for (int mk = 16; mk >= 1; mk >>= 1) {                           \
            float vo = __shfl_xor(v_, mk);                               \
            int co   = __shfl_xor(c_, mk);                               \
            if (vo > v_ || (vo == v_ && co < c_)) { v_ = vo; c_ = co; }  \
        }                                                                \
        if (c_ == ch) {                                                  \
            const int tt_ = (TIDX);                                      \
            const uint32_t bit_ = 1u << (tt_ & 31);                      \
            switch (tt_ >> 5) {     /* wave-uniform branch */            \
                case 0: m0 |= bit_; break;                               \
                case 1: m1 |= bit_; break;                               \
                case 2: m2 |= bit_; break;                               \
                case 3: m3 |= bit_; break;                               \
                default: m4 |= bit_; break;                              \
            }                                                            \
        }                                                                \
    }

// ---------------------------------------------------------------------------
// Kernel 1: build + sum-rows + 4-step jump-scan; masks to d_ws. PURE
// LDS/VALU kernel this round: the 293 MB zero-fill has been MOVED OUT
// (decomposition experiment: is the scan ~150us of compute, or was the
// in-kernel fill drain the hidden binder?). Only 11.8 MB ws written here.
// Block = 4 waves = sites x0..x0+3 sharing one table set (9 columns).
// Wave lanes: 0-31 = 32 ch x trains 0-8 (ci=0); 32-63 = same ch x 9-17.
// Entry k = (C[k]<<16)|M[k]: C = #spikes before time k, M = sum of times.
// GROUP-CLAMP LAYOUT: 4 leading zero entries (-4..-1) and dup-tail entries
// (101..103); one clamp of the group base index to [-4,100] makes the 4
// reads {entry i..i+3} return exactly T[clamp(i+k,0,100)] for each step k.
// NO inline asm with register operands (round-3/4 permlane corruption).
// ---------------------------------------------------------------------------
__global__ __launch_bounds__(256) void snn_scan(
    const float* __restrict__ in,
    const float* __restrict__ weight,
    float* __restrict__ out,
    uint32_t* __restrict__ ws)
{
    __shared__ uint32_t tbl[(NROWS + NSUM) * RSTRIDE];

    const int tid  = threadIdx.x;
    const int wave = tid >> 6;
    const int lane = tid & 63;
    const int half = lane >> 5;
    const int ch   = lane & 31;

    const int bi = blockIdx.x;
    const int xg = bi & 7;                // 8 x-groups of 4 (last has 3)
    const int y  = (bi >> 3) % NYS;
    const int b  = bi / (8 * NYS);
    const int x0 = xg * 4;
    const int x  = x0 + wave;             // this wave's site (x>=31 inactive)

    // per-lane response params: r(tau)=tau/16 for tau<=m=floor(16w);
    // (48w-tau)/32 for m<tau<=n=ceil(48w)-1.
    // qm/qn: entry index for window edge = (tp-1) - m = tp + q, q = -1-m.
    float wA[9]; int qm[9], qn[9];
    {
        const float* wrow = weight + ch * 18 + half * 9;
#pragma unroll
        for (int j = 0; j < 9; ++j) {
            float w = wrow[j];
            float a48 = 48.0f * w;
            int m = (int)floorf(16.0f * w);
            int n = (int)ceilf(a48) - 1;
            if (n < m) n = m;
            wA[j] = a48; qm[j] = -1 - m; qn[j] = -1 - n;
        }
    }

    // ---- build 54 rows; row r owned by one lane (waves split the rows).
    // Word W = entry W-4 = P[W-4]; front uint4 = zeros; chunk c stores
    // entries 4c..4c+3 at words 4c+4..4c+7 (16B aligned); tail uint4 =
    // entries 100..103 = {P100,dup,dup,dup}.
    {
        const int r = lane + 14 * wave;    // lanes 0..13 of each wave
        if (lane < 14 && r < NROWS) {
            const int ci = r / 27, rem = r % 27;
            const int ky = rem / 9, col = rem % 9;
            const int h = 2 * y + ky, wc = 2 * x0 + col;
            if (wc < 64) {                 // xg=7,col=8 is OOB and unused
                const float4* rowp = (const float4*)(in +
                    (size_t)(((b * 2 + ci) * 64 + h) * 64 + wc) * TT);
                uint32_t* t = tbl + r * RSTRIDE;
                *((uint4*)t) = make_uint4(0u, 0u, 0u, 0u);   // entries -4..-1
                uint32_t R = 0;                               // P[4c]
#pragma unroll 5
                for (int chunk = 0; chunk < 25; ++chunk) {
                    float4 v = rowp[chunk];
                    const uint32_t u = chunk * 4;
                    uint32_t i0 = (v.x > 0.5f) ? ((1u << 16) | u)       : 0u;
                    uint32_t i1 = (v.y > 0.5f) ? ((1u << 16) | (u + 1)) : 0u;
                    uint32_t i2 = (v.z > 0.5f) ? ((1u << 16) | (u + 2)) : 0u;
                    uint32_t i3 = (v.w > 0.5f) ? ((1u << 16) | (u + 3)) : 0u;
                    uint32_t s01 = i0 + i1, s012 = s01 + i2;
                    *((uint4*)(t + 4 + u)) = make_uint4(R, R + i0, R + s01, R + s012);
                    R += s012 + i3;        // single dependent add per chunk
                }
                // entries 100..103 = {P[100], dup, dup, dup}
                *((uint4*)(t + 104)) = make_uint4(R, R, R, R);
            }
        }
    }
    __syncthreads();

    // ---- build 8 per-(site,half) sum rows: word-wise sum of the 9 rows
    // (27 uint4 = words 0..107). Packed sums stay carry-free (C<=900,
    // M<=44550). Zero/dup pads sum to zero/dup-of-sum. Inactive site 31's
    // rows sum garbage -> never read.
    {
        const int sr = tid >> 5;           // 0..7 = wave*2 + half
        const int L  = tid & 31;
        if (L < 27) {
            const int w2 = sr >> 1, h2 = sr & 1;
            const uint32_t* bse = tbl + (h2 * 27 + 2 * w2) * RSTRIDE + 4 * L;
            uint4 acc = make_uint4(0u, 0u, 0u, 0u);
#pragma unroll
            for (int q = 0; q < 9; ++q) {
                const uint4 v = *(const uint4*)(bse + ((q / 3) * 9 + (q % 3)) * RSTRIDE);
                acc.x += v.x; acc.y += v.y; acc.z += v.z; acc.w += v.w;
            }
            *(uint4*)(tbl + (NROWS + sr) * RSTRIDE + 4 * L) = acc;
        }
    }
    __syncthreads();

    // ---- 4-step grouped jump-scan WTA ----
    uint32_t m0 = 0, m1 = 0, m2 = 0, m3 = 0, m4 = 0;   // 149-bit spike mask
    if (x < NXS) {
        // entry-0 pointers (word 4 of each row)
        const uint32_t* Tq = tbl + (half * 27 + 2 * wave) * RSTRIDE + 4;
        const uint32_t* Sq = tbl + (NROWS + wave * 2 + half) * RSTRIDE + 4;
        const uint32_t* Trow[9];
#pragma unroll
        for (int j = 0; j < 9; ++j)
            Trow[j] = Tq + ((j / 3) * 9 + (j % 3)) * RSTRIDE;

        int tp = 1;                        // tp=0: empty window, no spike
        while (tp <= TP - 1) {
            const int V = TP - tp;                     // valid steps (>=1)
            // P0 row: entries min(tp+k,100), exact via dup tail
            const int is = (tp > TT) ? TT : tp;        // wave-uniform
            const uint32_t* ps = Sq + is;
            const uint32_t s0 = ps[0], s1 = ps[1], s2 = ps[2], s3 = ps[3];
            uint32_t P1[4] = {0u, 0u, 0u, 0u};
            uint32_t D2[4] = {0u, 0u, 0u, 0u};
            float    Fw[4] = {0.f, 0.f, 0.f, 0.f};
#pragma unroll
            for (int j = 0; j < 9; ++j) {
                int i1 = tp + qm[j];                   // (tp-1) - m_j
                i1 = i1 < -4 ? -4 : (i1 > TT ? TT : i1);   // med3
                int i2 = tp + qn[j];                   // (tp-1) - n_j
                i2 = i2 < -4 ? -4 : (i2 > TT ? TT : i2);   // med3
                const uint32_t* p1 = Trow[j] + i1;
                const uint32_t* p2 = Trow[j] + i2;
#pragma unroll
                for (int k = 0; k < 4; ++k) {
                    const uint32_t e1 = p1[k], e2 = p2[k];  // ds_read2 pairs
                    const uint32_t dd = e1 - e2;       // packed, carry-free
                    P1[k] += e1;
                    D2[k] += dd;
                    Fw[k] += wA[j] * (float)(dd >> 16);    // count <= 47
                }
            }
            // packed sums/differences carry-free: sum C<=900, sum M<=44550.
            float cb0, cb1, cb2, cb3;
#pragma unroll
            for (int k = 0; k < 4; ++k) {
                const uint32_t sk = (k == 0) ? s0 : (k == 1) ? s1 : (k == 2) ? s2 : s3;
                const float ftk = (float)(tp - 1 + k);
                const uint32_t D1 = sk - P1[k];        // rising window totals
                float pot = (ftk * (float)(D1 >> 16) - (float)(D1 & 0xffffu)) * 0.0625f
                          + (Fw[k] - ftk * (float)(D2[k] >> 16) + (float)(D2[k] & 0xffffu)) * 0.03125f;
                pot += __shfl_xor(pot, 32);     // combine the two train halves
                if (k == 0) cb0 = pot; else if (k == 1) cb1 = pot;
                else if (k == 2) cb2 = pot; else cb3 = pot;
            }
            float mx = cb0;
            if (V > 1) mx = fmaxf(mx, cb1);
            if (V > 2) mx = fmaxf(mx, cb2);
            if (V > 3) mx = fmaxf(mx, cb3);
            if (!__ballot(mx > 5.4f)) { tp += 4; continue; }
            // slow path: resolve steps in order (exact sequential semantics)
            if (__ballot(cb0 > 5.4f))          { RECORD_WIN(cb0, tp);     tp += 48; continue; }
            if (V > 1 && __ballot(cb1 > 5.4f)) { RECORD_WIN(cb1, tp + 1); tp += 49; continue; }
            if (V > 2 && __ballot(cb2 > 5.4f)) { RECORD_WIN(cb2, tp + 2); tp += 50; continue; }
            if (V > 3 && __ballot(cb3 > 5.4f)) { RECORD_WIN(cb3, tp + 3); tp += 51; continue; }
            tp += 4;
        }
    }

    // ---- write this (site,ch) mask record (24 B, records contiguous per
    // block -> 768 B per wave, coalesced). Inactive waves write zeros. ----
    if (lane < 32) {
        uint32_t* rec = ws + ((size_t)bi * 128 + wave * 32 + ch) * 6;
        rec[0] = m0; rec[1] = m1; rec[2] = m2; rec[3] = m3; rec[4] = m4;
    }
}

// ---------------------------------------------------------------------------
// Kernel 2: region-owned output writer (fill + scatter fused). One WAVE per
// (b,ch,y) strip = NXS*TP = 4619 contiguous floats. The wave float4-zero-
// fills its strip (alignment prologue/tail handled: strip starts are only
// dword-aligned since 149 is odd), drains its own stores with vmcnt(0),
// then lanes 0..30 overwrite the <=4 spike positions of their site from
// the ws record. All writes to a strip come from its owning wave, so the
// single in-wave waitcnt fully orders zero -> spike. Kernel boundary
// orders kernel 1's ws writes before our reads.
// HBM: 293 MB write + 11.8 MB read (ws likely L2-resident) ~= 50 us.
// ---------------------------------------------------------------------------
__global__ __launch_bounds__(256) void snn_out(
    const uint32_t* __restrict__ ws,
    float* __restrict__ out)
{
    const int tid  = threadIdx.x;
    const int wave = tid >> 6;
    const int lane = tid & 63;
    const int wid  = blockIdx.x * 4 + wave;   // 0..15871 = (b*32+ch)*31 + y
    const int y    = wid % NYS;
    const int bc   = wid / NYS;               // b*32 + ch
    const int ch   = bc & 31;
    const int b    = bc >> 5;

    const size_t start = (size_t)(bc * 961 + y * NYS) * TP;  // strip base
    // ---- zero-fill strip [start, start+4619): head to 16B alignment,
    // float4 body, tail.
    const int a0   = (int)((4 - ((int)(start & 3))) & 3);
    const int nb   = (RLEN - a0) >> 2;
    const int tail = RLEN - a0 - (nb << 2);
    if (lane < a0)   out[start + lane] = 0.0f;
    {
        float4* p4 = (float4*)(out + start + a0);
        const float4 z4 = make_float4(0.f, 0.f, 0.f, 0.f);
        for (int i = lane; i < nb; i += 64)
            p4[i] = z4;
    }
    if (lane < tail) out[start + a0 + (nb << 2) + lane] = 0.0f;

    // order this wave's zero stores before its spike stores (cross-lane
    // same-address ordering is not otherwise guaranteed).
    asm volatile("s_waitcnt vmcnt(0)" ::: "memory");

    // ---- spike overwrites: lane x in [0,31) owns site (x, this strip).
    if (lane < NXS) {
        const int x = lane;
        const int r = (((b * NYS + y) * 8 + (x >> 2)) * 128) + (x & 3) * 32 + ch;
        const uint32_t* rec = ws + (size_t)r * 6;
        const uint32_t w0 = rec[0], w1 = rec[1], w2 = rec[2];
        const uint32_t w3 = rec[3], w4 = rec[4];
        if ((w0 | w1 | w2 | w3 | w4) != 0u) {
            const size_t base = start + (size_t)x * TP;
            uint32_t mw[5] = { w0, w1, w2, w3, w4 };
#pragma unroll
            for (int w = 0; w < 5; ++w) {
                uint32_t mm = mw[w];
                while (mm) {               // <=4 spikes total per (site,ch)
                    const int t = __builtin_ctz(mm);
                    mm &= mm - 1;
                    out[base + 32 * w + t] = 1.0f;
                }
            }
        }
    }
}

extern "C" void kernel_launch(void* const* d_in, const int* in_sizes, int n_in,
                              void* d_out, int out_size, void* d_ws, size_t ws_size,
                              hipStream_t stream) {
    const float* in = (const float*)d_in[0];   // input_spikes
    const float* wt = (const float*)d_in[1];   // weight
    float* out = (float*)d_out;
    uint32_t* ws = (uint32_t*)d_ws;            // 492032 * 24 B = 11.8 MB

    hipLaunchKernelGGL(snn_scan, dim3(NBLK), dim3(256), 0, stream,
                       in, wt, out, ws);
    hipLaunchKernelGGL(snn_out, dim3(NBLK), dim3(256), 0, stream,
                       ws, out);
}

// Round 8
// 361.200 us; speedup vs baseline: 1.0771x; 1.0771x over previous
//
#include <hip/hip_runtime.h>
#include <stdint.h>

// Spiking ConvColumn: temporal PWL-response conv + winner-takes-all.
//   input_spikes [16, 2, 64, 64, 100] fp32 (binary)
//   weight       [32, 2, 3, 3]        fp32 in [0,1]
//   output       [16, 32, 31, 31, 149] fp32 (one-hot spikes)
#define NXS 31
#define NYS 31
#define TP 149
#define TT 100
#define RSTRIDE 104         // u32/row; word W = entry W-1: word0 = 0 (entry
                            // -1), words 1..101 = entries 0..100, 102/103 =
                            // dup(T[100]); %4==0 keeps b128 alignment
#define NROWS 54            // 2 ci * 3 ky * 9 cols (4 sites share 9 cols)
#define NSUM 8              // per-(site,half) precomputed sum rows
                            // LDS = 62*104*4 = 25.8 KB -> 6 blk/CU
#define NBLK (16 * NYS * 8) // 3968 blocks
#define FILL4 4619          // float4s per block: 3968*4619 = 18328192 exact
#define NREC (NBLK * 128)   // 492032 (site,ch) mask records in d_ws

// argmax over 32 channels; ties -> lowest ch (jnp.argmax); both halves hold
// the combined pot, shuffles with mk<=16 stay inside each half.
#define RECORD_WIN(POTV, TIDX)                                           \
    {                                                                    \
        float v_ = (POTV); int c_ = ch;                                  \
        _Pragma("unroll")                                                \
        for (int mk = 16; mk >= 1; mk >>= 1) {                           \
            float vo = __shfl_xor(v_, mk);                               \
            int co   = __shfl_xor(c_, mk);                               \
            if (vo > v_ || (vo == v_ && co < c_)) { v_ = vo; c_ = co; }  \
        }                                                                \
        if (c_ == ch) {                                                  \
            const int tt_ = (TIDX);                                      \
            const uint32_t bit_ = 1u << (tt_ & 31);                      \
            switch (tt_ >> 5) {     /* wave-uniform branch */            \
                case 0: m0 |= bit_; break;                               \
                case 1: m1 |= bit_; break;                               \
                case 2: m2 |= bit_; break;                               \
                case 3: m3 |= bit_; break;                               \
                default: m4 |= bit_; break;                              \
            }                                                            \
        }                                                                \
    }

// Cross-half combine: every lane gets pot[l] + pot[l^32]. The permlane32
// builtin is VALU-only (no LDS round trip) and compiler-understood (the
// round-3/4 inline-asm version corrupted results; the BUILTIN is safe).
// r[0] = {lo,lo}, r[1] = {hi,hi} when both inputs are pot -> r0+r1 is the
// same two-operand float add as pot + shfl_xor(pot,32), bit-identical.
__device__ __forceinline__ float combine_halves(float pot) {
#if defined(__has_builtin) && __has_builtin(__builtin_amdgcn_permlane32_swap)
    const unsigned u = __float_as_uint(pot);
    const auto r = __builtin_amdgcn_permlane32_swap(u, u, false, false);
    return __uint_as_float(r[0]) + __uint_as_float(r[1]);
#else
    return pot + __shfl_xor(pot, 32);
#endif
}

// ---------------------------------------------------------------------------
// Kernel 1: build + sum-rows + linear-fill-issue + 2-step jump-scan; masks
// to d_ws. Round-2-proven base (359.9us) with two serial-chain cuts:
// (1) ONE fast-path ballot on max(cbA,cbB) per 2-step group (slow path
//     resolves steps in order -> bit-identical sequential decisions);
// (2) permlane32_swap BUILTIN for the cross-half combine (VALU) instead of
//     two shfl_xor LDS round-trips on the dependency chain.
// Zero-fill stays IN this kernel (round-7 decomposition: in-scan fill costs
// ~+20us hidden vs ~55us standalone). Placed after the last barrier so no
// vmcnt wait lands before kernel end (scan is LDS/VALU-only).
// Block = 4 waves = sites x0..x0+3 sharing one table set (9 columns).
// Wave lanes: 0-31 = 32 ch x trains 0-8 (ci=0); 32-63 = same ch x 9-17.
// Entry k = (C[k]<<16)|M[k]: C = #spikes before time k, M = sum of times.
// ---------------------------------------------------------------------------
__global__ __launch_bounds__(256) void snn_scan(
    const float* __restrict__ in,
    const float* __restrict__ weight,
    float* __restrict__ out,
    uint32_t* __restrict__ ws)
{
    __shared__ uint32_t tbl[(NROWS + NSUM) * RSTRIDE];

    const int tid  = threadIdx.x;
    const int wave = tid >> 6;
    const int lane = tid & 63;
    const int half = lane >> 5;
    const int ch   = lane & 31;

    const int bi = blockIdx.x;
    const int xg = bi & 7;                // 8 x-groups of 4 (last has 3)
    const int y  = (bi >> 3) % NYS;
    const int b  = bi / (8 * NYS);
    const int x0 = xg * 4;
    const int x  = x0 + wave;             // this wave's site (x>=31 inactive)

    // per-lane response params: r(tau)=tau/16 for tau<=m=floor(16w);
    // (48w-tau)/32 for m<tau<=n=ceil(48w)-1.
    // qm/qn: entry index for window edge = (tp-1) - m = tp + q, q = -1-m.
    float wA[9]; int qm[9], qn[9];
    {
        const float* wrow = weight + ch * 18 + half * 9;
#pragma unroll
        for (int j = 0; j < 9; ++j) {
            float w = wrow[j];
            float a48 = 48.0f * w;
            int m = (int)floorf(16.0f * w);
            int n = (int)ceilf(a48) - 1;
            if (n < m) n = m;
            wA[j] = a48; qm[j] = -1 - m; qn[j] = -1 - n;
        }
    }

    // ---- build 54 rows; row r owned by one lane (waves split the rows).
    // Shifted layout: chunk c stores words 4c..4c+3 = P[4c-1..4c+2] where
    // P[k] = packed prefix over spikes at times < k. Carry A=P[4c-1], B=P[4c].
    {
        const int r = lane + 14 * wave;    // lanes 0..13 of each wave
        if (lane < 14 && r < NROWS) {
            const int ci = r / 27, rem = r % 27;
            const int ky = rem / 9, col = rem % 9;
            const int h = 2 * y + ky, wc = 2 * x0 + col;
            if (wc < 64) {                 // xg=7,col=8 is OOB and unused
                const float4* rowp = (const float4*)(in +
                    (size_t)(((b * 2 + ci) * 64 + h) * 64 + wc) * TT);
                uint32_t* t = tbl + r * RSTRIDE;      // word 0, 16B aligned
                uint32_t A = 0, B = 0;
#pragma unroll 5
                for (int chunk = 0; chunk < 25; ++chunk) {
                    float4 v = rowp[chunk];
                    const uint32_t u = chunk * 4;
                    uint32_t i0 = (v.x > 0.5f) ? ((1u << 16) | u)       : 0u;
                    uint32_t i1 = (v.y > 0.5f) ? ((1u << 16) | (u + 1)) : 0u;
                    uint32_t i2 = (v.z > 0.5f) ? ((1u << 16) | (u + 2)) : 0u;
                    uint32_t i3 = (v.w > 0.5f) ? ((1u << 16) | (u + 3)) : 0u;
                    uint32_t s01 = i0 + i1;
                    *((uint4*)(t + u)) = make_uint4(A, B, B + i0, B + s01);
                    A = B + s01 + i2;      // P[4c+3]
                    B = A + i3;            // P[4c+4]
                }
                // words 100..103 = {P[99], P[100], dup, dup}
                *((uint4*)(t + 100)) = make_uint4(A, B, B, B);
            }
        }
    }
    __syncthreads();

    // ---- build 8 per-(site,half) sum rows: word-wise sum of the 9 rows.
    // Packed sums stay carry-free (C<=900, M<=44550). Zero word stays zero,
    // dup words stay dup-of-sum. Inactive site 31's rows sum garbage ->
    // never read.
    {
        const int sr = tid >> 5;           // 0..7 = wave*2 + half
        const int L  = tid & 31;
        if (L < 26) {
            const int w2 = sr >> 1, h2 = sr & 1;
            const uint32_t* bse = tbl + (h2 * 27 + 2 * w2) * RSTRIDE + 4 * L;
            uint4 acc = make_uint4(0u, 0u, 0u, 0u);
#pragma unroll
            for (int q = 0; q < 9; ++q) {
                const uint4 v = *(const uint4*)(bse + ((q / 3) * 9 + (q % 3)) * RSTRIDE);
                acc.x += v.x; acc.y += v.y; acc.z += v.z; acc.w += v.w;
            }
            *(uint4*)(tbl + (NROWS + sr) * RSTRIDE + 4 * L) = acc;
        }
    }
    __syncthreads();

    // ---- issue linear zero-fill chunk (fire-and-forget; drains under scan).
    {
        float4* out4 = (float4*)out + (size_t)bi * FILL4;
        const float4 z4 = make_float4(0.f, 0.f, 0.f, 0.f);
        for (int i = tid; i < FILL4; i += 256)
            out4[i] = z4;
    }

    // ---- 2-step jump-scan WTA, single fast-path ballot per group ----
    uint32_t m0 = 0, m1 = 0, m2 = 0, m3 = 0, m4 = 0;   // 149-bit spike mask
    if (x < NXS) {
        // entry-0 pointers (word 1 of each row)
        const uint32_t* Tq = tbl + (half * 27 + 2 * wave) * RSTRIDE + 1;
        const uint32_t* Sq = tbl + (NROWS + wave * 2 + half) * RSTRIDE + 1;
        const uint32_t* Trow[9];
#pragma unroll
        for (int j = 0; j < 9; ++j)
            Trow[j] = Tq + ((j / 3) * 9 + (j % 3)) * RSTRIDE;

        int tp = 1;                        // tp=0: empty window, no spike
        while (tp < TP) {
            const float ft1 = (float)(tp - 1);
            // P0: S[min(tp,100)] / S[min(tp+1,100)] via pair read (dup tail)
            const int is = tp > TT ? TT : tp;          // wave-uniform
            const uint32_t* ps = Sq + is;
            const uint32_t sl = ps[0], sh = ps[1];     // ds_read2_b32
            uint32_t P1A = 0, P2A = 0, P1B = 0, P2B = 0;
            float FA = 0.0f, FB = 0.0f;    // sum_j 48w_j * dc2_j
#pragma unroll
            for (int j = 0; j < 9; ++j) {
                int i1 = tp + qm[j];                   // (tp-1) - m_j
                i1 = i1 > TT ? TT : i1; i1 = i1 < -1 ? -1 : i1;   // med3
                int i2 = tp + qn[j];                   // (tp-1) - n_j
                i2 = i2 > TT ? TT : i2; i2 = i2 < -1 ? -1 : i2;   // med3
                const uint32_t* p1 = Trow[j] + i1;
                const uint32_t* p2 = Trow[j] + i2;
                const uint32_t lo1 = p1[0], hi1 = p1[1];  // ds_read2_b32
                const uint32_t lo2 = p2[0], hi2 = p2[1];  // ds_read2_b32
                P1A += lo1; P2A += lo2;                // step A edge sums
                P1B += hi1; P2B += hi2;                // step B edge sums
                FA += wA[j] * (float)((lo1 - lo2) >> 16);
                FB += wA[j] * (float)((hi1 - hi2) >> 16);
            }
            // packed sums/differences carry-free: sum C<=900, sum M<=44550.
            const uint32_t D1A = sl - P1A;     // rising window totals (A)
            const uint32_t D2A = P1A - P2A;    // falling window totals (A)
            float potA = (ft1 * (float)(D1A >> 16) - (float)(D1A & 0xffffu)) * 0.0625f
                       + (FA - ft1 * (float)(D2A >> 16) + (float)(D2A & 0xffffu)) * 0.03125f;
            const float cbA = combine_halves(potA);

            const float ftB = (float)tp;
            const uint32_t D1B = sh - P1B;     // P0B = sh always (dup tail)
            const uint32_t D2B = P1B - P2B;
            float potB = (ftB * (float)(D1B >> 16) - (float)(D1B & 0xffffu)) * 0.0625f
                       + (FB - ftB * (float)(D2B >> 16) + (float)(D2B & 0xffffu)) * 0.03125f;
            const float cbB = combine_halves(potB);

            const bool hasB = (tp != TP - 1);  // step B would be t=149
            const float mx = hasB ? fmaxf(cbA, cbB) : cbA;
            if (!__ballot(mx > 5.4f)) { tp += 2; continue; }   // fast path
            // slow path: resolve steps in order (exact sequential semantics)
            if (__ballot(cbA > 5.4f)) { RECORD_WIN(cbA, tp); tp += 48; continue; }
            if (hasB && __ballot(cbB > 5.4f)) { RECORD_WIN(cbB, tp + 1); tp += 49; continue; }
            tp += 2;
        }
    }

    // ---- write this (site,ch) mask record (24 B, records contiguous per
    // block -> 768 B per wave, coalesced). Inactive waves write zeros. ----
    if (lane < 32) {
        uint32_t* rec = ws + ((size_t)bi * 128 + wave * 32 + ch) * 6;
        rec[0] = m0; rec[1] = m1; rec[2] = m2; rec[3] = m3; rec[4] = m4;
    }
}

// ---------------------------------------------------------------------------
// Kernel 2: scatter the 1.0s. One thread per (site,ch) record; coalesced
// 24-B read, early-out if no spikes (~69%), else <=4 scattered stores.
// Kernel boundary guarantees kernel 1's zeros are visible first.
// ---------------------------------------------------------------------------
__global__ __launch_bounds__(256) void snn_scatter(
    const uint32_t* __restrict__ ws,
    float* __restrict__ out)
{
    const int r = blockIdx.x * 256 + threadIdx.x;        // 0..NREC-1
    const uint32_t* rec = ws + (size_t)r * 6;
    const uint32_t m0 = rec[0], m1 = rec[1], m2 = rec[2];
    const uint32_t m3 = rec[3], m4 = rec[4];
    if ((m0 | m1 | m2 | m3 | m4) == 0u) return;

    const int ch = r & 31;
    const int wave = (r >> 5) & 3;
    const int bi = r >> 7;
    const int xg = bi & 7;
    const int y  = (bi >> 3) % NYS;
    const int b  = bi / (8 * NYS);
    const int x  = xg * 4 + wave;                        // x<31 (else mask==0)
    const size_t base = (size_t)(((b * 32 + ch) * 961) + y * NYS + x) * TP;

    uint32_t mw[5] = { m0, m1, m2, m3, m4 };
#pragma unroll
    for (int w = 0; w < 5; ++w) {
        uint32_t mm = mw[w];
        while (mm) {                       // <=4 spikes total per (site,ch)
            const int t = __builtin_ctz(mm);
            mm &= mm - 1;
            out[base + 32 * w + t] = 1.0f;
        }
    }
}

extern "C" void kernel_launch(void* const* d_in, const int* in_sizes, int n_in,
                              void* d_out, int out_size, void* d_ws, size_t ws_size,
                              hipStream_t stream) {
    const float* in = (const float*)d_in[0];   // input_spikes
    const float* wt = (const float*)d_in[1];   // weight
    float* out = (float*)d_out;
    uint32_t* ws = (uint32_t*)d_ws;            // 492032 * 24 B = 11.8 MB

    hipLaunchKernelGGL(snn_scan, dim3(NBLK), dim3(256), 0, stream,
                       in, wt, out, ws);
    hipLaunchKernelGGL(snn_scatter, dim3(NREC / 256), dim3(256), 0, stream,
                       ws, out);
}